// Round 1
// baseline (123.825 us; speedup 1.0000x reference)
//
#include <hip/hip_runtime.h>
#include <math.h>

#define BB 128
#define PP 1024
#define LL 128
#define NROWS (BB * PP)   // 131072
#define EPS_VAR 1e-5f

// robust NaN test (immune to -ffast-math folding of v!=v)
__device__ __forceinline__ bool is_nan_bits(float f) {
    return (__float_as_uint(f) & 0x7fffffffu) > 0x7f800000u;
}

// ---------------------------------------------------------------------------
// Kernel 1: per-row (b,p) NaN-aware sum, sum-of-squares, nan count.
// One wave handles 2 rows: lanes 0..31 -> row r, lanes 32..63 -> row r+1.
// Each lane loads one float4 (16B); a wave covers 1024 contiguous bytes.
// ---------------------------------------------------------------------------
__global__ __launch_bounds__(256) void k_rowstats(const float* __restrict__ x,
                                                  float4* __restrict__ stats) {
    const int wave = threadIdx.x >> 6;   // 0..3
    const int lane = threadIdx.x & 63;
    const int half = lane >> 5;          // which row of the pair
    const int sl   = lane & 31;          // sub-lane within the row
    const int row  = (blockIdx.x * 4 + wave) * 2 + half;

    const float4 v = ((const float4*)(x + (size_t)row * LL))[sl];

    float s1 = 0.f, s2 = 0.f, c = 0.f;
    {
        const float f[4] = {v.x, v.y, v.z, v.w};
#pragma unroll
        for (int j = 0; j < 4; ++j) {
            const bool nn = is_nan_bits(f[j]);
            const float vv = nn ? 0.f : f[j];
            s1 += vv;
            s2 += vv * vv;
            c  += nn ? 1.f : 0.f;
        }
    }
    // butterfly reduce within each 32-lane half (masks < 32 never cross halves)
#pragma unroll
    for (int off = 16; off >= 1; off >>= 1) {
        s1 += __shfl_xor(s1, off);
        s2 += __shfl_xor(s2, off);
        c  += __shfl_xor(c,  off);
    }
    if (sl == 0) stats[row] = make_float4(s1, s2, c, 0.f);
}

// ---------------------------------------------------------------------------
// Kernel 2: per-b inclusive scan over P of (s1, s2, nancnt); emit mean, 1/std.
// One block per b, 1024 threads, Hillis-Steele in LDS.
// ---------------------------------------------------------------------------
__global__ __launch_bounds__(1024) void k_scan(const float4* __restrict__ stats,
                                               float2* __restrict__ ms) {
    __shared__ float a1[PP];
    __shared__ float a2[PP];
    __shared__ float ac[PP];

    const int t = threadIdx.x;
    const int b = blockIdx.x;

    const float4 s = stats[(size_t)b * PP + t];
    a1[t] = s.x; a2[t] = s.y; ac[t] = s.z;
    __syncthreads();

#pragma unroll
    for (int off = 1; off < PP; off <<= 1) {
        float v1 = 0.f, v2 = 0.f, vc = 0.f;
        if (t >= off) { v1 = a1[t - off]; v2 = a2[t - off]; vc = ac[t - off]; }
        __syncthreads();
        if (t >= off) { a1[t] += v1; a2[t] += v2; ac[t] += vc; }
        __syncthreads();
    }

    const float cnt  = (float)(t + 1) * (float)LL - ac[t];
    const float mean = a1[t] / cnt;
    const float var  = a2[t] / cnt - mean * mean;
    const float istd = 1.0f / sqrtf(var + EPS_VAR);
    ms[(size_t)b * PP + t] = make_float2(mean, istd);
}

// ---------------------------------------------------------------------------
// Kernel 3: out = (x - mean) * istd, with NaN forward-fill fallback.
// Same 2-rows-per-wave float4 layout as kernel 1.
// ---------------------------------------------------------------------------
__global__ __launch_bounds__(256) void k_norm(const float* __restrict__ x,
                                              const float2* __restrict__ ms,
                                              float* __restrict__ out) {
    const int wave = threadIdx.x >> 6;
    const int lane = threadIdx.x & 63;
    const int half = lane >> 5;
    const int sl   = lane & 31;
    const int row  = (blockIdx.x * 4 + wave) * 2 + half;
    const size_t base = (size_t)row * LL;

    const float4 v = ((const float4*)(x + base))[sl];
    const float2 m = ms[row];

    float4 y;
    y.x = (v.x - m.x) * m.y;
    y.y = (v.y - m.x) * m.y;
    y.z = (v.z - m.x) * m.y;
    y.w = (v.w - m.x) * m.y;

    const bool n0 = is_nan_bits(v.x), n1 = is_nan_bits(v.y);
    const bool n2 = is_nan_bits(v.z), n3 = is_nan_bits(v.w);
    const bool anynan = n0 | n1 | n2 | n3;

    if (__ballot(anynan) == 0ull) {
        // fast path (always taken for this input): vectorized store
        ((float4*)(out + base))[sl] = y;
    } else {
        // slow path: per-element forward fill along L (never taken in bench)
        const float yy[4] = {y.x, y.y, y.z, y.w};
        const bool  nn[4] = {n0, n1, n2, n3};
#pragma unroll
        for (int j = 0; j < 4; ++j) {
            const int l = sl * 4 + j;
            if (!nn[j]) {
                out[base + l] = yy[j];
            } else {
                float res = 0.0f;  // x_temp[0] == 0 when no prior valid exists
                for (int k = l - 1; k >= 0; --k) {
                    const float xv = x[base + k];
                    if (!is_nan_bits(xv)) { res = (xv - m.x) * m.y; break; }
                }
                out[base + l] = res;
            }
        }
    }
}

extern "C" void kernel_launch(void* const* d_in, const int* in_sizes, int n_in,
                              void* d_out, int out_size, void* d_ws, size_t ws_size,
                              hipStream_t stream) {
    const float* x = (const float*)d_in[0];
    float* out = (float*)d_out;

    float4* stats = (float4*)d_ws;                                      // 2 MiB
    float2* ms    = (float2*)((char*)d_ws + (size_t)NROWS * sizeof(float4)); // 1 MiB

    // 2 rows/wave * 4 waves/block = 8 rows per block
    k_rowstats<<<NROWS / 8, 256, 0, stream>>>(x, stats);
    k_scan<<<BB, PP, 0, stream>>>(stats, ms);
    k_norm<<<NROWS / 8, 256, 0, stream>>>(x, ms, out);
}

// Round 3
// 120.635 us; speedup vs baseline: 1.0264x; 1.0264x over previous
//
#include <hip/hip_runtime.h>
#include <math.h>

#define BB 128
#define PP 1024
#define LL 128
#define NROWS (BB * PP)   // 131072
#define EPS_VAR 1e-5f

typedef float vfloat4 __attribute__((ext_vector_type(4)));  // clang-native, OK for nontemporal builtins

__device__ __forceinline__ bool is_nan_bits(float f) {
    return (__float_as_uint(f) & 0x7fffffffu) > 0x7f800000u;
}

// ---------------------------------------------------------------------------
// Kernel 1: per-row (b,p) NaN-aware sum, sum-of-squares, nan count.
// Each 32-lane half-wave handles 2 consecutive rows (2 float4 loads/thread
// in flight for ILP). Butterfly reduce within the 32-lane half.
// ---------------------------------------------------------------------------
__global__ __launch_bounds__(256) void k_rowstats(const float* __restrict__ x,
                                                  float4* __restrict__ stats) {
    const int sl = threadIdx.x & 31;                       // sub-lane in half-wave
    const int hw = (blockIdx.x * 256 + threadIdx.x) >> 5;  // global half-wave id
    const int row0 = hw * 2;
    const int row1 = row0 + 1;

    const float4 v0 = ((const float4*)(x + (size_t)row0 * LL))[sl];
    const float4 v1 = ((const float4*)(x + (size_t)row1 * LL))[sl];

    float s1a = 0.f, s2a = 0.f, ca = 0.f;
    float s1b = 0.f, s2b = 0.f, cb = 0.f;
    {
        const float fa[4] = {v0.x, v0.y, v0.z, v0.w};
        const float fb[4] = {v1.x, v1.y, v1.z, v1.w};
#pragma unroll
        for (int j = 0; j < 4; ++j) {
            const bool na = is_nan_bits(fa[j]);
            const float va = na ? 0.f : fa[j];
            s1a += va; s2a += va * va; ca += na ? 1.f : 0.f;
            const bool nb = is_nan_bits(fb[j]);
            const float vb = nb ? 0.f : fb[j];
            s1b += vb; s2b += vb * vb; cb += nb ? 1.f : 0.f;
        }
    }
#pragma unroll
    for (int off = 16; off >= 1; off >>= 1) {
        s1a += __shfl_xor(s1a, off);
        s2a += __shfl_xor(s2a, off);
        ca  += __shfl_xor(ca,  off);
        s1b += __shfl_xor(s1b, off);
        s2b += __shfl_xor(s2b, off);
        cb  += __shfl_xor(cb,  off);
    }
    if (sl == 0) {
        stats[row0] = make_float4(s1a, s2a, ca, 0.f);
        stats[row1] = make_float4(s1b, s2b, cb, 0.f);
    }
}

// ---------------------------------------------------------------------------
// Kernel 2: per-b inclusive scan over P of (s1, s2, nancnt); emit mean, 1/std.
// One block of 256 threads per b. Thread t serially scans rows [4t, 4t+4),
// 6-step shuffle scan across the wave, single barrier for 4 wave totals.
// ---------------------------------------------------------------------------
__global__ __launch_bounds__(256) void k_scan(const float4* __restrict__ stats,
                                              float2* __restrict__ ms) {
    __shared__ float w1[4], w2[4], wc[4];

    const int t    = threadIdx.x;
    const int lane = t & 63;
    const int wav  = t >> 6;
    const int b    = blockIdx.x;
    const size_t base = (size_t)b * PP + t * 4;

    float4 r[4];
#pragma unroll
    for (int j = 0; j < 4; ++j) r[j] = stats[base + j];

    // serial inclusive scan of the 4 local rows
    float i1[4], i2[4], ic[4];
    i1[0] = r[0].x; i2[0] = r[0].y; ic[0] = r[0].z;
#pragma unroll
    for (int j = 1; j < 4; ++j) {
        i1[j] = i1[j - 1] + r[j].x;
        i2[j] = i2[j - 1] + r[j].y;
        ic[j] = ic[j - 1] + r[j].z;
    }
    const float t1 = i1[3], t2 = i2[3], tc = ic[3];

    // wave-level inclusive shuffle scan of the per-thread totals
    float c1 = t1, c2 = t2, cc = tc;
#pragma unroll
    for (int off = 1; off < 64; off <<= 1) {
        const float a   = __shfl_up(c1, off);
        const float bb2 = __shfl_up(c2, off);
        const float cc2 = __shfl_up(cc, off);
        if (lane >= off) { c1 += a; c2 += bb2; cc += cc2; }
    }
    // exclusive prefix for this thread within the wave
    const float e1 = c1 - t1, e2 = c2 - t2, ec = cc - tc;

    if (lane == 63) { w1[wav] = c1; w2[wav] = c2; wc[wav] = cc; }
    __syncthreads();

    float p1 = 0.f, p2 = 0.f, pc = 0.f;
#pragma unroll
    for (int k = 0; k < 3; ++k) {
        if (wav > k) { p1 += w1[k]; p2 += w2[k]; pc += wc[k]; }
    }

    const float b1 = p1 + e1, b2 = p2 + e2, bc = pc + ec;
    float2 o[4];
#pragma unroll
    for (int j = 0; j < 4; ++j) {
        const int p = t * 4 + j;
        const float cum1 = b1 + i1[j];
        const float cum2 = b2 + i2[j];
        const float cumc = bc + ic[j];
        const float cnt  = (float)(p + 1) * (float)LL - cumc;
        const float mean = cum1 / cnt;
        const float var  = cum2 / cnt - mean * mean;
        const float istd = 1.0f / sqrtf(var + EPS_VAR);
        o[j] = make_float2(mean, istd);
    }
    float2* dst = ms + base;
#pragma unroll
    for (int j = 0; j < 4; ++j) dst[j] = o[j];
}

// ---------------------------------------------------------------------------
// Kernel 3: out = (x - mean) * istd, NaN forward-fill fallback.
// Each 32-lane half-wave handles 2 consecutive rows, float4 I/O,
// nontemporal stores (out is write-once).
// ---------------------------------------------------------------------------
__global__ __launch_bounds__(256) void k_norm(const float* __restrict__ x,
                                              const float2* __restrict__ ms,
                                              float* __restrict__ out) {
    const int sl = threadIdx.x & 31;
    const int hw = (blockIdx.x * 256 + threadIdx.x) >> 5;
    const int row0 = hw * 2;
    const int row1 = row0 + 1;
    const size_t base0 = (size_t)row0 * LL;
    const size_t base1 = (size_t)row1 * LL;

    const float4 v0 = ((const float4*)(x + base0))[sl];
    const float4 v1 = ((const float4*)(x + base1))[sl];
    const float2 m0 = ms[row0];
    const float2 m1 = ms[row1];

    float4 y0, y1;
    y0.x = (v0.x - m0.x) * m0.y; y0.y = (v0.y - m0.x) * m0.y;
    y0.z = (v0.z - m0.x) * m0.y; y0.w = (v0.w - m0.x) * m0.y;
    y1.x = (v1.x - m1.x) * m1.y; y1.y = (v1.y - m1.x) * m1.y;
    y1.z = (v1.z - m1.x) * m1.y; y1.w = (v1.w - m1.x) * m1.y;

    const bool anynan = is_nan_bits(v0.x) | is_nan_bits(v0.y) | is_nan_bits(v0.z) |
                        is_nan_bits(v0.w) | is_nan_bits(v1.x) | is_nan_bits(v1.y) |
                        is_nan_bits(v1.z) | is_nan_bits(v1.w);

    if (__ballot(anynan) == 0ull) {
        // fast path: vectorized nontemporal stores via clang-native vector type
        vfloat4 w0 = {y0.x, y0.y, y0.z, y0.w};
        vfloat4 w1 = {y1.x, y1.y, y1.z, y1.w};
        __builtin_nontemporal_store(w0, &((vfloat4*)(out + base0))[sl]);
        __builtin_nontemporal_store(w1, &((vfloat4*)(out + base1))[sl]);
    } else {
        // slow path (never taken on NaN-free bench input)
        const size_t bases[2] = {base0, base1};
        const float2 mm[2] = {m0, m1};
        const float4 vv[2] = {v0, v1};
        const float4 yy[2] = {y0, y1};
#pragma unroll
        for (int rr = 0; rr < 2; ++rr) {
            const float yf[4] = {yy[rr].x, yy[rr].y, yy[rr].z, yy[rr].w};
            const float vf[4] = {vv[rr].x, vv[rr].y, vv[rr].z, vv[rr].w};
            for (int j = 0; j < 4; ++j) {
                const int l = sl * 4 + j;
                if (!is_nan_bits(vf[j])) {
                    out[bases[rr] + l] = yf[j];
                } else {
                    float res = 0.0f;  // x_temp[0]==0 when no prior valid exists
                    for (int k = l - 1; k >= 0; --k) {
                        const float xv = x[bases[rr] + k];
                        if (!is_nan_bits(xv)) {
                            res = (xv - mm[rr].x) * mm[rr].y;
                            break;
                        }
                    }
                    out[bases[rr] + l] = res;
                }
            }
        }
    }
}

extern "C" void kernel_launch(void* const* d_in, const int* in_sizes, int n_in,
                              void* d_out, int out_size, void* d_ws, size_t ws_size,
                              hipStream_t stream) {
    const float* x = (const float*)d_in[0];
    float* out = (float*)d_out;

    float4* stats = (float4*)d_ws;                                           // 2 MiB
    float2* ms    = (float2*)((char*)d_ws + (size_t)NROWS * sizeof(float4)); // 1 MiB

    // 2 rows per half-wave -> 16 rows per 256-thread block
    k_rowstats<<<NROWS / 16, 256, 0, stream>>>(x, stats);
    k_scan<<<BB, 256, 0, stream>>>(stats, ms);
    k_norm<<<NROWS / 16, 256, 0, stream>>>(x, ms, out);
}